// Round 8
// baseline (121.275 us; speedup 1.0000x reference)
//
#include <hip/hip_runtime.h>
#include <math.h>

#define NOBS 45
typedef float2 c32;

// wire -> storage-bit map: w0,w1 local (bits 1,0); w2..w7 lane bits 5,4,3,1,0,2 (storage 7,6,5,3,2,4); w8,w9 wave (9,8)
constexpr int W2Sc[10] = {1, 0, 7, 6, 5, 3, 2, 4, 9, 8};
constexpr int OAc[NOBS] = {
    0,0,0,0,0,0,0,0,0, 1,1,1,1,1,1,1,1, 2,2,2,2,2,2,2, 3,3,3,3,3,3,
    4,4,4,4,4, 5,5,5,5, 6,6,6, 7,7, 8};
constexpr int OBc[NOBS] = {
    1,2,3,4,5,6,7,8,9, 2,3,4,5,6,7,8,9, 3,4,5,6,7,8,9, 4,5,6,7,8,9,
    5,6,7,8,9, 6,7,8,9, 7,8,9, 8,9, 9};
constexpr int TIc[6] = {1, 2, 2, 3, 3, 3};
constexpr int TJc[6] = {0, 0, 1, 0, 1, 2};

__device__ __forceinline__ c32 cfma(c32 a, c32 b, c32 c) {
    c.x = fmaf(a.x, b.x, fmaf(-a.y, b.y, c.x));
    c.y = fmaf(a.x, b.y, fmaf(a.y, b.x, c.y));
    return c;
}
__device__ __forceinline__ c32 cmul(c32 a, c32 b) {
    return make_float2(a.x * b.x - a.y * b.y, a.x * b.y + a.y * b.x);
}

// ---------------- cross-lane exchange on the VALU pipe ----------------
template <int CTRL>
__device__ __forceinline__ float dppf(float x) {
    return __uint_as_float((unsigned)__builtin_amdgcn_update_dpp(
        0, (int)__float_as_uint(x), CTRL, 0xF, 0xF, true));
}
// lane^32 via v_permlane32_swap; sum-minus-self is convention-immune (HW-validated r2-r7)
__device__ __forceinline__ float swap32f(float a) {
    auto r = __builtin_amdgcn_permlane32_swap(__float_as_uint(a), __float_as_uint(a), false, false);
    return (__uint_as_float(r[0]) + __uint_as_float(r[1])) - a;
}
#if __has_builtin(__builtin_amdgcn_permlane16_swap)
__device__ __forceinline__ float swap16f(float a) {
    auto r = __builtin_amdgcn_permlane16_swap(__float_as_uint(a), __float_as_uint(a), false, false);
    return (__uint_as_float(r[0]) + __uint_as_float(r[1])) - a;
}
#else
__device__ __forceinline__ float swap16f(float a) { return __shfl_xor(a, 16, 64); }
#endif
__device__ __forceinline__ float swz4f(float a) {  // lane^4 via ds_swizzle
    return __uint_as_float(__builtin_amdgcn_ds_swizzle(__float_as_uint(a), 0x101F));
}
template <int M>
__device__ __forceinline__ float exf(float x) {
    float r = x;
    if constexpr ((M & 3) == 1) r = dppf<0xB1>(r);        // quad_perm [1,0,3,2]
    else if constexpr ((M & 3) == 2) r = dppf<0x4E>(r);   // quad_perm [2,3,0,1]
    else if constexpr ((M & 3) == 3) r = dppf<0x1B>(r);   // quad_perm [3,2,1,0]
    if constexpr (M & 4)  r = swz4f(r);
    if constexpr (M & 8)  r = dppf<0x128>(r);             // row_ror:8 == lane^8 (within 16)
    if constexpr (M & 16) r = swap16f(r);
    if constexpr (M & 32) r = swap32f(r);
    return r;
}
template <int M>
__device__ __forceinline__ c32 exch(c32 a) { return make_float2(exf<M>(a.x), exf<M>(a.y)); }
__device__ __forceinline__ c32 swap32c(c32 a) { return make_float2(swap32f(a.x), swap32f(a.y)); }

// full-wave sum via DPP adds; total lands in lane 63
__device__ __forceinline__ float wave_reduce63(float x) {
    x += dppf<0x111>(x);  // row_shr:1
    x += dppf<0x112>(x);  // row_shr:2
    x += dppf<0x114>(x);  // row_shr:4
    x += dppf<0x118>(x);  // row_shr:8
    x += dppf<0x142>(x);  // row_bcast15
    x += dppf<0x143>(x);  // row_bcast31
    return x;
}

__device__ __forceinline__ int insert2(int t, int pl, int ph) {
    int low  = t & ((1 << pl) - 1);
    int rest = t >> pl;
    int nm   = ph - 1 - pl;
    int mid  = rest & ((1 << nm) - 1);
    int high = rest >> nm;
    return low | (mid << (pl + 1)) | (high << (ph + 1));
}

// Pauli 2x2 entry, word W in {0=I,1=X,2=Y,3=Z}
template <int W>
__device__ __forceinline__ c32 pE(int r, int c) {
    if constexpr (W == 0) return make_float2((r == c) ? 1.f : 0.f, 0.f);
    else if constexpr (W == 1) return make_float2((r != c) ? 1.f : 0.f, 0.f);
    else if constexpr (W == 2) return make_float2(0.f, (r == c) ? 0.f : ((r == 0) ? -1.f : 1.f));
    else return make_float2((r == c) ? ((r == 0) ? 1.f : -1.f) : 0.f, 0.f);
}
template <int W0, int W1>
__device__ __forceinline__ void paccum(c32& H, float th, int i1, int i2, int j1, int j2) {
    c32 a = pE<W0>(i1, j1), b = pE<W1>(i2, j2);
    c32 p = cmul(a, b);
    H.x = fmaf(th, p.x, H.x);
    H.y = fmaf(th, p.y, H.y);
}

// ---------- gate fragments ----------
struct F16 { c32 u[16]; };
struct FLoc { c32 a[4]; c32 b[4]; };
struct F4 { c32 uS, uB, uA, uC; };

__device__ __forceinline__ F16 loadF16(const c32* __restrict__ U) {
    F16 f;
#pragma unroll
    for (int i = 0; i < 16; i++) f.u[i] = U[i];
    return f;
}
__device__ __forceinline__ FLoc loadLoc(const c32* __restrict__ U, int ln) {
    int bb = (ln >> 5) & 1;
    const c32* U0 = U + bb * 4;
    const c32* U1 = U + (2 | bb) * 4;
    int c00 = bb, c01 = 2 | bb, c10 = bb ^ 1, c11 = 2 | (bb ^ 1);
    FLoc f;
    f.a[0] = U0[c00]; f.a[1] = U0[c01]; f.a[2] = U0[c10]; f.a[3] = U0[c11];
    f.b[0] = U1[c00]; f.b[1] = U1[c01]; f.b[2] = U1[c10]; f.b[3] = U1[c11];
    return f;
}
template <int QA, int QB>
__device__ __forceinline__ F4 loadL2(const c32* __restrict__ U, int ln) {
    int bA = (ln >> QA) & 1, bB = (ln >> QB) & 1;
    int r = (bA << 1) | bB;
    const c32* Ur = U + r * 4;
    F4 f;
    f.uS = Ur[r]; f.uB = Ur[r ^ 1]; f.uA = Ur[r ^ 2]; f.uC = Ur[r ^ 3];
    return f;
}

__device__ __forceinline__ void applyLL(c32 v[4], const F16& f) {
    c32 n0 = cfma(f.u[0],  v[0], cfma(f.u[1],  v[1], cfma(f.u[2],  v[2], cmul(f.u[3],  v[3]))));
    c32 n1 = cfma(f.u[4],  v[0], cfma(f.u[5],  v[1], cfma(f.u[6],  v[2], cmul(f.u[7],  v[3]))));
    c32 n2 = cfma(f.u[8],  v[0], cfma(f.u[9],  v[1], cfma(f.u[10], v[2], cmul(f.u[11], v[3]))));
    c32 n3 = cfma(f.u[12], v[0], cfma(f.u[13], v[1], cfma(f.u[14], v[2], cmul(f.u[15], v[3]))));
    v[0] = n0; v[1] = n1; v[2] = n2; v[3] = n3;
}
__device__ __forceinline__ void applyLoc(c32 v[4], const FLoc& f) {
    c32 p0 = swap32c(v[0]), p1 = swap32c(v[1]), p2 = swap32c(v[2]), p3 = swap32c(v[3]);
    c32 n0 = cfma(f.a[0], v[0], cfma(f.a[1], v[1], cfma(f.a[2], p0, cmul(f.a[3], p1))));
    c32 n1 = cfma(f.b[0], v[0], cfma(f.b[1], v[1], cfma(f.b[2], p0, cmul(f.b[3], p1))));
    c32 n2 = cfma(f.a[0], v[2], cfma(f.a[1], v[3], cfma(f.a[2], p2, cmul(f.a[3], p3))));
    c32 n3 = cfma(f.b[0], v[2], cfma(f.b[1], v[3], cfma(f.b[2], p2, cmul(f.b[3], p3))));
    v[0] = n0; v[1] = n1; v[2] = n2; v[3] = n3;
}
template <int QA, int QB>
__device__ __forceinline__ void applyL2(c32 v[4], const F4& f) {
#pragma unroll
    for (int lc = 0; lc < 4; lc++) {
        c32 pB = exch<(1 << QB)>(v[lc]);
        c32 pA = exch<(1 << QA)>(v[lc]);
        c32 pC = exch<(1 << QA)>(pB);
        v[lc] = cfma(f.uS, v[lc], cfma(f.uB, pB, cfma(f.uA, pA, cmul(f.uC, pC))));
    }
}

// ---------- flat psi storage (per-element region) ----------
__device__ __forceinline__ void dumpV(const c32 v[4], c32* __restrict__ psi, int tt) {
#pragma unroll
    for (int lc = 0; lc < 4; lc++) psi[(tt << 2) | lc] = v[lc];
}
__device__ __forceinline__ void loadV(c32 v[4], const c32* __restrict__ psi, int tt) {
#pragma unroll
    for (int lc = 0; lc < 4; lc++) v[lc] = psi[(tt << 2) | lc];
}
template <int PA, int PB>
__device__ __forceinline__ void ldsApply(const F16& f, c32* __restrict__ psi, int tt) {
    constexpr int PL = (PA < PB) ? PA : PB, PH = (PA < PB) ? PB : PA;
    int base = insert2(tt, PL, PH);
    constexpr int oa = 1 << PA, ob = 1 << PB;
    c32 g0 = psi[base], g1 = psi[base + ob], g2 = psi[base + oa], g3 = psi[base + oa + ob];
    c32 n0 = cfma(f.u[0],  g0, cfma(f.u[1],  g1, cfma(f.u[2],  g2, cmul(f.u[3],  g3))));
    c32 n1 = cfma(f.u[4],  g0, cfma(f.u[5],  g1, cfma(f.u[6],  g2, cmul(f.u[7],  g3))));
    c32 n2 = cfma(f.u[8],  g0, cfma(f.u[9],  g1, cfma(f.u[10], g2, cmul(f.u[11], g3))));
    c32 n3 = cfma(f.u[12], g0, cfma(f.u[13], g1, cfma(f.u[14], g2, cmul(f.u[15], g3))));
    psi[base] = n0; psi[base + ob] = n1; psi[base + oa] = n2; psi[base + oa + ob] = n3;
}

// 512 threads = 2 batch elements per block (2 waves/SIMD for latency hiding)
__global__ __launch_bounds__(512, 2) void mega_kernel(
    const float* __restrict__ x,  const float* __restrict__ W1, const float* __restrict__ b1,
    const float* __restrict__ W2, const float* __restrict__ b2, const float* __restrict__ qp,
    const float* __restrict__ Am, const float* __restrict__ Bm, const float* __restrict__ Dm,
    float* __restrict__ out) {
    __shared__ __align__(16) c32 psiS[2048];  // per-elem scratch (MLP/expm/prep) then psi; 16KB
    __shared__ c32 UeS[288];       // 2 x 9 encoding unitaries
    __shared__ c32 GpS[720];       // 45 fused pyramid gates (shared, batch-independent)
    __shared__ float HbS[720];     // 45 compact Hermitians (shared)
    __shared__ float encS[2][136];
    __shared__ float redS[2][180];

    const int t = threadIdx.x, elem = t >> 8, tt = t & 255, ln = t & 63;
    const int row = blockIdx.x * 2 + elem;
    c32* psiE = psiS + (elem << 10);
    c32* UeE  = UeS + elem * 144;
    float* F = (float*)psiE;  // 2048 floats of per-elem scratch

    // ================= Phase 1: MLP (each elem on its 256-thread half) =================
    if (tt < 128) ((float4*)F)[tt] = ((const float4*)(x + (size_t)row * 512))[tt];
    __syncthreads();
    {
        int q = tt & 63, sl = tt >> 6;
        float4 a4 = make_float4(0.f, 0.f, 0.f, 0.f);
#pragma unroll 16
        for (int kk = 0; kk < 128; kk++) {
            int k = sl * 128 + kk;
            float xk = F[k];
            const float4 w = *(const float4*)(W1 + (size_t)k * 256 + q * 4);
            a4.x = fmaf(xk, w.x, a4.x); a4.y = fmaf(xk, w.y, a4.y);
            a4.z = fmaf(xk, w.z, a4.z); a4.w = fmaf(xk, w.w, a4.w);
        }
        *(float4*)(F + 512 + sl * 256 + q * 4) = a4;
    }
    __syncthreads();
    {
        float hv = b1[tt] + F[512 + tt] + F[768 + tt] + F[1024 + tt] + F[1280 + tt];
        hv = hv / (1.f + __expf(-hv));      // silu
        F[1536 + tt] = hv;
    }
    __syncthreads();
    if (tt < 135) {
        float a2 = b2[tt], a3 = 0.f;
#pragma unroll 16
        for (int k = 0; k < 128; k++) {
            a2 = fmaf(F[1536 + k],       W2[(size_t)k * 135 + tt],         a2);
            a3 = fmaf(F[1536 + 128 + k], W2[(size_t)(128 + k) * 135 + tt], a3);
        }
        encS[elem][tt] = a2 + a3;
    }
    __syncthreads();

    // ========== Phase 2+3: expm (tt<144, both elems) | prep (elem0: 144..233) | Hb (elem0: 234..255) ==========
    // expm: exp(iH) = exp(iH/64)^64, Taylor deg 7
    c32* Mm = psiE;        // per-elem [0,144)
    c32* Rb = psiE + 144;  // per-elem [144,288)
    c32* TA = psiS + 288;  // elem0 region [288,1008) prep ping; pong = GpS
    if (tt < 144) {
        int m = tt >> 4, e = tt & 15, i = e >> 2, j = e & 3;
        int i1 = i >> 1, i2 = i & 1, j1 = j >> 1, j2 = j & 1;
        const float* th = encS[elem] + m * 15;
        c32 H = make_float2(0.f, 0.f);
        paccum<0,1>(H, th[0],  i1,i2,j1,j2); paccum<0,2>(H, th[1],  i1,i2,j1,j2);
        paccum<0,3>(H, th[2],  i1,i2,j1,j2); paccum<1,0>(H, th[3],  i1,i2,j1,j2);
        paccum<1,1>(H, th[4],  i1,i2,j1,j2); paccum<1,2>(H, th[5],  i1,i2,j1,j2);
        paccum<1,3>(H, th[6],  i1,i2,j1,j2); paccum<2,0>(H, th[7],  i1,i2,j1,j2);
        paccum<2,1>(H, th[8],  i1,i2,j1,j2); paccum<2,2>(H, th[9],  i1,i2,j1,j2);
        paccum<2,3>(H, th[10], i1,i2,j1,j2); paccum<3,0>(H, th[11], i1,i2,j1,j2);
        paccum<3,1>(H, th[12], i1,i2,j1,j2); paccum<3,2>(H, th[13], i1,i2,j1,j2);
        paccum<3,3>(H, th[14], i1,i2,j1,j2);
        const float sc = 1.f / 64.f;
        Mm[tt] = make_float2(-H.y * sc, H.x * sc);                  // i*H/64
        Rb[tt] = make_float2((i == j) ? 1.f : 0.f, 0.f);            // R = I
    } else if (elem == 0 && tt >= 234) {
        for (int w = tt - 234; w < NOBS; w += 22) {
            float* Hf = HbS + w * 16;
            Hf[0] = 2.f * Dm[w * 4 + 1];
            Hf[1] = 2.f * Dm[w * 4 + 2];
            Hf[2] = 2.f * Dm[w * 4 + 3];
            Hf[3] = 0.f;
#pragma unroll
            for (int k = 0; k < 6; k++) {
                Hf[4 + 2 * k] = 2.f * Am[w * 6 + k];
                Hf[5 + 2 * k] = 2.f * Bm[w * 6 + k];
            }
        }
    }
    __syncthreads();
    c32 Mrow[4];
    if (tt < 144) {
        int m = tt >> 4, i = (tt & 15) >> 2;
#pragma unroll
        for (int k = 0; k < 4; k++) Mrow[k] = Mm[m * 16 + i * 4 + k];
    }
#pragma unroll 1
    for (int step = 0; step < 13; step++) {   // expm: 7 Horner + 6 squarings; prep: steps 0..7
        if (tt < 144) {
            int m = tt >> 4, e = tt & 15, i = e >> 2, j = e & 3;
            const c32* cur = (step & 1) ? UeE : Rb;
            c32 acc = make_float2(0.f, 0.f);
            c32 outv;
            if (step < 7) {
#pragma unroll
                for (int k = 0; k < 4; k++) acc = cfma(Mrow[k], cur[m * 16 + k * 4 + j], acc);
                float inv = 1.f / (float)(7 - step);
                outv = make_float2(fmaf(acc.x, inv, (i == j) ? 1.f : 0.f), acc.y * inv);
            } else {
#pragma unroll
                for (int k = 0; k < 4; k++)
                    acc = cfma(cur[m * 16 + i * 4 + k], cur[m * 16 + k * 4 + j], acc);
                outv = acc;
            }
            ((step & 1) ? Rb : UeE)[tt] = outv;
        } else if (elem == 0 && tt >= 144 && tt < 234 && step < 8) {
            int pt = tt - 144, g = pt >> 1, ih = (pt & 1) << 1;
            const float* p = qp + g * 12;
            const c32* src = ((step & 1) ? TA : GpS) + g * 16;
            c32* dst = ((step & 1) ? GpS : TA) + g * 16;
#pragma unroll
            for (int r2 = 0; r2 < 2; r2++) {
                int i = ih + r2, i1 = i >> 1, i2 = i & 1;
                c32 rowv[4];
                if (step == 0) {
                    float s, c; __sincosf(p[0] * 0.5f, &s, &c);
                    c32 u0, u1;
                    if (i1 == 0) { u0 = make_float2(c, 0.f);
                                   u1 = make_float2(-__cosf(p[2]) * s, -__sinf(p[2]) * s); }
                    else { u0 = make_float2(__cosf(p[1]) * s, __sinf(p[1]) * s);
                           u1 = make_float2(__cosf(p[1] + p[2]) * c, __sinf(p[1] + p[2]) * c); }
#pragma unroll
                    for (int jj = 0; jj < 4; jj++) rowv[jj] = make_float2(0.f, 0.f);
                    rowv[i2] = u0; rowv[2 | i2] = u1;
                } else {
                    c32 coef0, coef1; int c0, c1;
                    if (step == 1 || step == 5) {              // XX
                        float s, c; __sincosf(p[step == 1 ? 3 : 9] * 0.5f, &s, &c);
                        c0 = i; coef0 = make_float2(c, 0.f);
                        c1 = i ^ 3; coef1 = make_float2(0.f, -s);
                    } else if (step == 2 || step == 6) {       // YY
                        float s, c; __sincosf(p[step == 2 ? 4 : 10] * 0.5f, &s, &c);
                        float yy = (i == 0 || i == 3) ? 1.f : -1.f;
                        c0 = i; coef0 = make_float2(c, 0.f);
                        c1 = i ^ 3; coef1 = make_float2(0.f, s * yy);
                    } else if (step == 3 || step == 7) {       // ZZ (diag)
                        float s, c; __sincosf(p[step == 3 ? 5 : 11] * 0.5f, &s, &c);
                        float zz = (i == 0 || i == 3) ? 1.f : -1.f;
                        c0 = i; coef0 = make_float2(c, -s * zz);
                        c1 = i; coef1 = make_float2(0.f, 0.f);
                    } else {                                    // step 4: U3b (high qubit)
                        float s, c; __sincosf(p[6] * 0.5f, &s, &c);
                        if (i1 == 0) { coef0 = make_float2(c, 0.f);
                                       coef1 = make_float2(-__cosf(p[8]) * s, -__sinf(p[8]) * s); }
                        else { coef0 = make_float2(__cosf(p[7]) * s, __sinf(p[7]) * s);
                               coef1 = make_float2(__cosf(p[7] + p[8]) * c, __sinf(p[7] + p[8]) * c); }
                        c0 = i2; c1 = 2 | i2;
                    }
#pragma unroll
                    for (int jj = 0; jj < 4; jj++)
                        rowv[jj] = cfma(coef0, src[c0 * 4 + jj], cmul(coef1, src[c1 * 4 + jj]));
                }
#pragma unroll
                for (int jj = 0; jj < 4; jj++) dst[i * 4 + jj] = rowv[jj];
            }
        }
        __syncthreads();
    }

    // ================= Phase 4: state-vector simulation =================
    c32 v[4];
#pragma unroll
    for (int lc = 0; lc < 4; lc++) v[lc] = make_float2(0.f, 0.f);
    if (tt == 0) v[0] = make_float2(1.f, 0.f);

    // encoding brick layer: (0,1)(2,3)(4,5)(6,7)(8,9)(1,2)(3,4)(5,6)(7,8)
    applyLL(v, loadF16(UeE + 0));
    applyL2<5, 4>(v, loadL2<5, 4>(UeE + 16, ln));
    applyL2<3, 1>(v, loadL2<3, 1>(UeE + 32, ln));
    applyL2<0, 2>(v, loadL2<0, 2>(UeE + 48, ln));
    dumpV(v, psiE, tt); __syncthreads();
    ldsApply<9, 8>(loadF16(UeE + 64), psiE, tt); __syncthreads();
    loadV(v, psiE, tt);
    applyLoc(v, loadLoc(UeE + 80, ln));
    applyL2<4, 3>(v, loadL2<4, 3>(UeE + 96, ln));
    applyL2<1, 0>(v, loadL2<1, 0>(UeE + 112, ln));
    dumpV(v, psiE, tt); __syncthreads();
    ldsApply<4, 9>(loadF16(UeE + 128), psiE, tt); __syncthreads();
    loadV(v, psiE, tt);

    // pyramid (fully unrolled, compile-time amax; GpS shared by both elems)
    {
        int g = 0;
#pragma unroll
        for (int layer = 0; layer < 9; layer++) {
            const int amax = 8 - layer;
            applyLL(v, loadF16(GpS + (g++) * 16));                               // (0,1)
            if (amax >= 1) applyLoc(v, loadLoc(GpS + (g++) * 16, ln));           // (1,2)
            if (amax >= 2) applyL2<5, 4>(v, loadL2<5, 4>(GpS + (g++) * 16, ln)); // (2,3)
            if (amax >= 3) applyL2<4, 3>(v, loadL2<4, 3>(GpS + (g++) * 16, ln)); // (3,4)
            if (amax >= 4) applyL2<3, 1>(v, loadL2<3, 1>(GpS + (g++) * 16, ln)); // (4,5)
            if (amax >= 5) applyL2<1, 0>(v, loadL2<1, 0>(GpS + (g++) * 16, ln)); // (5,6)
            if (amax >= 6) applyL2<0, 2>(v, loadL2<0, 2>(GpS + (g++) * 16, ln)); // (6,7)
            if (amax >= 7) {
                dumpV(v, psiE, tt); __syncthreads();
                ldsApply<4, 9>(loadF16(GpS + (g++) * 16), psiE, tt); __syncthreads();      // (7,8)
                if (amax >= 8) {
                    ldsApply<9, 8>(loadF16(GpS + (g++) * 16), psiE, tt); __syncthreads();  // (8,9)
                }
                loadV(v, psiE, tt);
            }
        }
    }

    // ================= Phase 5: observables (ILP x5, compact H, DPP reduce) =================
    dumpV(v, psiE, tt);
    __syncthreads();
#pragma unroll
    for (int w0 = 0; w0 < NOBS; w0 += 5) {
        float pr[5];
#pragma unroll
        for (int u = 0; u < 5; u++) {
            const int w = w0 + u;
            const int pa = W2Sc[OAc[w]], pb = W2Sc[OBc[w]];
            const int pl = (pa < pb) ? pa : pb, phh = (pa < pb) ? pb : pa;
            const int oa = 1 << pa, ob = 1 << pb;
            int i0 = insert2(tt, pl, phh);
            c32 vg[4];
            vg[0] = psiE[i0];      vg[1] = psiE[i0 + ob];
            vg[2] = psiE[i0 + oa]; vg[3] = psiE[i0 + oa + ob];
            const float* Hf = HbS + w * 16;
            float r = Hf[0] * fmaf(vg[0].x, vg[0].x, vg[0].y * vg[0].y)
                    + Hf[1] * fmaf(vg[1].x, vg[1].x, vg[1].y * vg[1].y)
                    + Hf[2] * fmaf(vg[2].x, vg[2].x, vg[2].y * vg[2].y);
#pragma unroll
            for (int k = 0; k < 6; k++) {
                c32 vi = vg[TIc[k]], vj = vg[TJc[k]];
                float cx = fmaf(vi.x, vj.x, vi.y * vj.y);
                float cy = fmaf(vi.x, vj.y, -vi.y * vj.x);
                r = fmaf(Hf[4 + 2 * k], cx, r);
                r = fmaf(-Hf[5 + 2 * k], cy, r);
            }
            pr[u] = wave_reduce63(r);
        }
        if (ln == 63) {
#pragma unroll
            for (int u = 0; u < 5; u++) redS[elem][(w0 + u) * 4 + (tt >> 6)] = pr[u];
        }
    }
    __syncthreads();
    if (tt < NOBS)
        out[(size_t)row * NOBS + tt] = redS[elem][tt * 4] + redS[elem][tt * 4 + 1]
                                     + redS[elem][tt * 4 + 2] + redS[elem][tt * 4 + 3];
}

extern "C" void kernel_launch(void* const* d_in, const int* in_sizes, int n_in,
                              void* d_out, int out_size, void* d_ws, size_t ws_size,
                              hipStream_t stream) {
    (void)in_sizes; (void)n_in; (void)out_size; (void)d_ws; (void)ws_size;
    const float* x  = (const float*)d_in[0];
    const float* W1 = (const float*)d_in[1];
    const float* b1 = (const float*)d_in[2];
    const float* W2 = (const float*)d_in[3];
    const float* b2 = (const float*)d_in[4];
    const float* qp = (const float*)d_in[5];
    const float* Am = (const float*)d_in[6];
    const float* Bm = (const float*)d_in[7];
    const float* Dm = (const float*)d_in[8];
    float* out = (float*)d_out;

    hipLaunchKernelGGL(mega_kernel, dim3(128), dim3(512), 0, stream,
                       x, W1, b1, W2, b2, qp, Am, Bm, Dm, out);
}

// Round 9
// 105.560 us; speedup vs baseline: 1.1489x; 1.1489x over previous
//
#include <hip/hip_runtime.h>
#include <math.h>

#define NOBS 45
typedef float2 c32;

// wire -> storage bit = IDENTITY. bit0 = local amp bit; bits1-6 = lane bits0-5; bits7-9 = wave bits0-2.
constexpr int OAc[NOBS] = {
    0,0,0,0,0,0,0,0,0, 1,1,1,1,1,1,1,1, 2,2,2,2,2,2,2, 3,3,3,3,3,3,
    4,4,4,4,4, 5,5,5,5, 6,6,6, 7,7, 8};
constexpr int OBc[NOBS] = {
    1,2,3,4,5,6,7,8,9, 2,3,4,5,6,7,8,9, 3,4,5,6,7,8,9, 4,5,6,7,8,9,
    5,6,7,8,9, 6,7,8,9, 7,8,9, 8,9, 9};

__device__ __forceinline__ c32 cfma(c32 a, c32 b, c32 c) {
    c.x = fmaf(a.x, b.x, fmaf(-a.y, b.y, c.x));
    c.y = fmaf(a.x, b.y, fmaf(a.y, b.x, c.y));
    return c;
}
__device__ __forceinline__ c32 cmul(c32 a, c32 b) {
    return make_float2(a.x * b.x - a.y * b.y, a.x * b.y + a.y * b.x);
}

// ---------------- cross-lane exchange on the VALU pipe ----------------
template <int CTRL>
__device__ __forceinline__ float dppf(float x) {
    return __uint_as_float((unsigned)__builtin_amdgcn_update_dpp(
        0, (int)__float_as_uint(x), CTRL, 0xF, 0xF, true));
}
// lane^32 via v_permlane32_swap; sum-minus-self is convention-immune (HW-validated r2-r8)
__device__ __forceinline__ float swap32f(float a) {
    auto r = __builtin_amdgcn_permlane32_swap(__float_as_uint(a), __float_as_uint(a), false, false);
    return (__uint_as_float(r[0]) + __uint_as_float(r[1])) - a;
}
#if __has_builtin(__builtin_amdgcn_permlane16_swap)
__device__ __forceinline__ float swap16f(float a) {
    auto r = __builtin_amdgcn_permlane16_swap(__float_as_uint(a), __float_as_uint(a), false, false);
    return (__uint_as_float(r[0]) + __uint_as_float(r[1])) - a;
}
#else
__device__ __forceinline__ float swap16f(float a) { return __shfl_xor(a, 16, 64); }
#endif
__device__ __forceinline__ float swz4f(float a) {  // lane^4 via ds_swizzle
    return __uint_as_float(__builtin_amdgcn_ds_swizzle(__float_as_uint(a), 0x101F));
}
template <int M>
__device__ __forceinline__ float exf(float x) {
    float r = x;
    if constexpr ((M & 3) == 1) r = dppf<0xB1>(r);        // quad_perm [1,0,3,2]
    else if constexpr ((M & 3) == 2) r = dppf<0x4E>(r);   // quad_perm [2,3,0,1]
    else if constexpr ((M & 3) == 3) r = dppf<0x1B>(r);   // quad_perm [3,2,1,0]
    if constexpr (M & 4)  r = swz4f(r);
    if constexpr (M & 8)  r = dppf<0x128>(r);             // row_ror:8 == lane^8 (within 16)
    if constexpr (M & 16) r = swap16f(r);
    if constexpr (M & 32) r = swap32f(r);
    return r;
}
template <int M>
__device__ __forceinline__ c32 exch(c32 a) { return make_float2(exf<M>(a.x), exf<M>(a.y)); }

// full-wave sum via DPP adds; total lands in lane 63
__device__ __forceinline__ float wave_reduce63(float x) {
    x += dppf<0x111>(x);  // row_shr:1
    x += dppf<0x112>(x);  // row_shr:2
    x += dppf<0x114>(x);  // row_shr:4
    x += dppf<0x118>(x);  // row_shr:8
    x += dppf<0x142>(x);  // row_bcast15
    x += dppf<0x143>(x);  // row_bcast31
    return x;
}

__device__ __forceinline__ int insert2(int t, int pl, int ph) {
    int low  = t & ((1 << pl) - 1);
    int rest = t >> pl;
    int nm   = ph - 1 - pl;
    int mid  = rest & ((1 << nm) - 1);
    int high = rest >> nm;
    return low | (mid << (pl + 1)) | (high << (ph + 1));
}

// Pauli 2x2 entry, word W in {0=I,1=X,2=Y,3=Z}
template <int W>
__device__ __forceinline__ c32 pE(int r, int c) {
    if constexpr (W == 0) return make_float2((r == c) ? 1.f : 0.f, 0.f);
    else if constexpr (W == 1) return make_float2((r != c) ? 1.f : 0.f, 0.f);
    else if constexpr (W == 2) return make_float2(0.f, (r == c) ? 0.f : ((r == 0) ? -1.f : 1.f));
    else return make_float2((r == c) ? ((r == 0) ? 1.f : -1.f) : 0.f, 0.f);
}
template <int W0, int W1>
__device__ __forceinline__ void paccum(c32& H, float th, int i1, int i2, int j1, int j2) {
    c32 a = pE<W0>(i1, j1), b = pE<W1>(i2, j2);
    c32 p = cmul(a, b);
    H.x = fmaf(th, p.x, H.x);
    H.y = fmaf(th, p.y, H.y);
}

// ---------- gate fragments (2 amps/thread) ----------
struct F8v { c32 u[8]; };
struct FLoc { c32 a[4]; c32 b[4]; };
struct F4 { c32 uS, uB, uA, uC; };

__device__ __forceinline__ F8v loadF8(const c32* __restrict__ U, int rr) {
    F8v f;
    const c32* R = U + (rr << 3);
#pragma unroll
    for (int i = 0; i < 8; i++) f.u[i] = R[i];
    return f;
}
// gate (0,1): local bit = wire0 (MSB), lane bit LB = wire1 (LSB)
template <int LB>
__device__ __forceinline__ FLoc loadLocLane(const c32* __restrict__ U, int ln) {
    int lb = (ln >> LB) & 1;
    const c32* R0 = U + lb * 4;        // row (0<<1)|lb
    const c32* R1 = U + (2 | lb) * 4;  // row (1<<1)|lb
    FLoc f;
    f.a[0] = R0[lb]; f.a[1] = R0[lb ^ 1]; f.a[2] = R0[2 | lb]; f.a[3] = R0[2 | (lb ^ 1)];
    f.b[0] = R1[lb]; f.b[1] = R1[lb ^ 1]; f.b[2] = R1[2 | lb]; f.b[3] = R1[2 | (lb ^ 1)];
    return f;
}
template <int LB>
__device__ __forceinline__ void applyLocLane(c32 v[2], const FLoc& f) {
    c32 p0 = exch<(1 << LB)>(v[0]);
    c32 p1 = exch<(1 << LB)>(v[1]);
    c32 n0 = cfma(f.a[3], p1, cfma(f.a[2], v[1], cfma(f.a[1], p0, cmul(f.a[0], v[0]))));
    c32 n1 = cfma(f.b[3], p1, cfma(f.b[2], v[1], cfma(f.b[1], p0, cmul(f.b[0], v[0]))));
    v[0] = n0; v[1] = n1;
}
// lane-lane gate: QA = lane bit of wire a (MSB), QB = lane bit of wire b
template <int QA, int QB>
__device__ __forceinline__ F4 loadL2(const c32* __restrict__ U, int ln) {
    int bA = (ln >> QA) & 1, bB = (ln >> QB) & 1;
    int r = (bA << 1) | bB;
    const c32* Ur = U + r * 4;
    F4 f;
    f.uS = Ur[r]; f.uB = Ur[r ^ 1]; f.uA = Ur[r ^ 2]; f.uC = Ur[r ^ 3];
    return f;
}
template <int QA, int QB>
__device__ __forceinline__ void applyL2(c32 v[2], const F4& f) {
    c32 pB[2], pA[2], pC[2];
#pragma unroll
    for (int lc = 0; lc < 2; lc++) pB[lc] = exch<(1 << QB)>(v[lc]);
#pragma unroll
    for (int lc = 0; lc < 2; lc++) pA[lc] = exch<(1 << QA)>(v[lc]);
#pragma unroll
    for (int lc = 0; lc < 2; lc++) pC[lc] = exch<(1 << QA)>(pB[lc]);
#pragma unroll
    for (int lc = 0; lc < 2; lc++)
        v[lc] = cfma(f.uC, pC[lc], cfma(f.uA, pA[lc], cfma(f.uB, pB[lc], cmul(f.uS, v[lc]))));
}

// ---------- psi in LDS, double-buffered for LDS-gate applies ----------
__device__ __forceinline__ void dumpV2(const c32 v[2], c32* __restrict__ psi, int t) {
    psi[t * 2] = v[0]; psi[t * 2 + 1] = v[1];
}
__device__ __forceinline__ void loadV2(c32 v[2], const c32* __restrict__ psi, int t) {
    v[0] = psi[t * 2]; v[1] = psi[t * 2 + 1];
}
// half-group apply: thread handles rows {2rr, 2rr+1} of group g; reads src, writes dst
template <int PA, int PB>  // PA < PB, wire a (MSB) = PA-wire
__device__ __forceinline__ void ldsApply2(const F8v& f, const c32* __restrict__ src,
                                          c32* __restrict__ dst, int g, int rr) {
    int base = insert2(g, PA, PB);
    constexpr int oa = 1 << PA, ob = 1 << PB;
    c32 g0 = src[base], g1 = src[base + ob], g2 = src[base + oa], g3 = src[base + oa + ob];
    c32 n0 = cfma(f.u[3], g3, cfma(f.u[2], g2, cfma(f.u[1], g1, cmul(f.u[0], g0))));
    c32 n1 = cfma(f.u[7], g3, cfma(f.u[6], g2, cfma(f.u[5], g1, cmul(f.u[4], g0))));
    dst[base + rr * oa] = n0;
    dst[base + rr * oa + ob] = n1;
}

// 512 threads, 1 batch element per block: 2 waves/SIMD on all 256 CUs
__global__ __launch_bounds__(512, 1) void mega_kernel(
    const float* __restrict__ x,  const float* __restrict__ W1, const float* __restrict__ b1,
    const float* __restrict__ W2, const float* __restrict__ b2, const float* __restrict__ qp,
    const float* __restrict__ Am, const float* __restrict__ Bm, const float* __restrict__ Dm,
    float* __restrict__ out) {
    __shared__ __align__(16) c32 psiS[2048];  // 16KB: MLP/expm/prep scratch, then psi A|B
    __shared__ c32 UeS[144];       // 9 encoding unitaries
    __shared__ c32 GpS[720];       // 45 fused pyramid gates
    __shared__ float HbS[720];     // 45 compact Hermitians: [2D0,2D1,2D2,pad, 6x(2A,2B)]
    __shared__ float encS0[136], encS1[136];
    __shared__ float redS[NOBS * 8];

    const int b = blockIdx.x, t = threadIdx.x, ln = t & 63;
    const int gg = t & 255, rr = t >> 8, wv = t >> 6;
    float* F = (float*)psiS;  // 4096 floats of scratch
    c32* psiA = psiS;
    c32* psiB = psiS + 1024;

    // ================= Phase 1: MLP =================
    if (t < 128) ((float4*)F)[t] = ((const float4*)(x + (size_t)b * 512))[t];
    __syncthreads();
    {
        int q = t & 63, sl = t >> 6;  // 8 k-slices of 64
        float4 a4 = make_float4(0.f, 0.f, 0.f, 0.f);
#pragma unroll 16
        for (int kk = 0; kk < 64; kk++) {
            int k = sl * 64 + kk;
            float xk = F[k];
            const float4 w = *(const float4*)(W1 + (size_t)k * 256 + q * 4);
            a4.x = fmaf(xk, w.x, a4.x); a4.y = fmaf(xk, w.y, a4.y);
            a4.z = fmaf(xk, w.z, a4.z); a4.w = fmaf(xk, w.w, a4.w);
        }
        *(float4*)(F + 512 + sl * 256 + q * 4) = a4;
    }
    __syncthreads();
    if (t < 256) {
        float hv = b1[t];
#pragma unroll
        for (int s = 0; s < 8; s++) hv += F[512 + s * 256 + t];
        hv = hv / (1.f + __expf(-hv));      // silu
        F[2560 + t] = hv;
    }
    __syncthreads();
    if (t < 135) {
        float a0 = b2[t], a1 = 0.f;
#pragma unroll 16
        for (int k = 0; k < 64; k++) {
            a0 = fmaf(F[2560 + k],      W2[(size_t)k * 135 + t],        a0);
            a1 = fmaf(F[2560 + 64 + k], W2[(size_t)(64 + k) * 135 + t], a1);
        }
        encS0[t] = a0 + a1;
    } else if (t >= 256 && t < 391) {
        int c = t - 256;
        float a0 = 0.f, a1 = 0.f;
#pragma unroll 16
        for (int k = 0; k < 64; k++) {
            a0 = fmaf(F[2560 + 128 + k], W2[(size_t)(128 + k) * 135 + c], a0);
            a1 = fmaf(F[2560 + 192 + k], W2[(size_t)(192 + k) * 135 + c], a1);
        }
        encS1[c] = a0 + a1;
    }
    __syncthreads();

    // ========== Phase 2+3: expm (t<144) | prep (144..233) | Hb (384..428) ==========
    c32* Mm = psiS;        // [0,144)
    c32* Rb = psiS + 144;  // [144,288)
    c32* TA = psiS + 288;  // [288,1008) prep ping; pong = GpS
    if (t < 144) {
        int m = t >> 4, e = t & 15, i = e >> 2, j = e & 3;
        int i1 = i >> 1, i2 = i & 1, j1 = j >> 1, j2 = j & 1;
        const int o = m * 15;
        c32 H = make_float2(0.f, 0.f);
#define TH(J) (encS0[o + (J)] + encS1[o + (J)])
        paccum<0,1>(H, TH(0),  i1,i2,j1,j2); paccum<0,2>(H, TH(1),  i1,i2,j1,j2);
        paccum<0,3>(H, TH(2),  i1,i2,j1,j2); paccum<1,0>(H, TH(3),  i1,i2,j1,j2);
        paccum<1,1>(H, TH(4),  i1,i2,j1,j2); paccum<1,2>(H, TH(5),  i1,i2,j1,j2);
        paccum<1,3>(H, TH(6),  i1,i2,j1,j2); paccum<2,0>(H, TH(7),  i1,i2,j1,j2);
        paccum<2,1>(H, TH(8),  i1,i2,j1,j2); paccum<2,2>(H, TH(9),  i1,i2,j1,j2);
        paccum<2,3>(H, TH(10), i1,i2,j1,j2); paccum<3,0>(H, TH(11), i1,i2,j1,j2);
        paccum<3,1>(H, TH(12), i1,i2,j1,j2); paccum<3,2>(H, TH(13), i1,i2,j1,j2);
        paccum<3,3>(H, TH(14), i1,i2,j1,j2);
#undef TH
        const float sc = 1.f / 64.f;
        Mm[t] = make_float2(-H.y * sc, H.x * sc);                  // i*H/64
        Rb[t] = make_float2((i == j) ? 1.f : 0.f, 0.f);            // R = I
    } else if (t >= 384 && t < 384 + NOBS) {
        const int w = t - 384;
        float* Hf = HbS + w * 16;
        Hf[0] = 2.f * Dm[w * 4 + 1];
        Hf[1] = 2.f * Dm[w * 4 + 2];
        Hf[2] = 2.f * Dm[w * 4 + 3];
        Hf[3] = 0.f;
#pragma unroll
        for (int k = 0; k < 6; k++) {
            Hf[4 + 2 * k] = 2.f * Am[w * 6 + k];
            Hf[5 + 2 * k] = 2.f * Bm[w * 6 + k];
        }
    }
    __syncthreads();
    c32 Mrow[4];
    if (t < 144) {
        int m = t >> 4, i = (t & 15) >> 2;
#pragma unroll
        for (int k = 0; k < 4; k++) Mrow[k] = Mm[m * 16 + i * 4 + k];
    }
#pragma unroll 1
    for (int step = 0; step < 13; step++) {   // expm: 7 Horner + 6 squarings; prep: steps 0..7
        if (t < 144) {
            int m = t >> 4, e = t & 15, i = e >> 2, j = e & 3;
            const c32* cur = (step & 1) ? UeS : Rb;
            c32 acc = make_float2(0.f, 0.f);
            c32 outv;
            if (step < 7) {
#pragma unroll
                for (int k = 0; k < 4; k++) acc = cfma(Mrow[k], cur[m * 16 + k * 4 + j], acc);
                float inv = 1.f / (float)(7 - step);
                outv = make_float2(fmaf(acc.x, inv, (i == j) ? 1.f : 0.f), acc.y * inv);
            } else {
#pragma unroll
                for (int k = 0; k < 4; k++)
                    acc = cfma(cur[m * 16 + i * 4 + k], cur[m * 16 + k * 4 + j], acc);
                outv = acc;
            }
            ((step & 1) ? Rb : UeS)[t] = outv;
        } else if (t >= 144 && t < 234 && step < 8) {
            int pt = t - 144, g = pt >> 1, ih = (pt & 1) << 1;
            const float* p = qp + g * 12;
            const c32* src = ((step & 1) ? TA : GpS) + g * 16;
            c32* dst = ((step & 1) ? GpS : TA) + g * 16;
#pragma unroll
            for (int r2 = 0; r2 < 2; r2++) {
                int i = ih + r2, i1 = i >> 1, i2 = i & 1;
                c32 rowv[4];
                if (step == 0) {
                    float s, c; __sincosf(p[0] * 0.5f, &s, &c);
                    c32 u0, u1;
                    if (i1 == 0) { u0 = make_float2(c, 0.f);
                                   u1 = make_float2(-__cosf(p[2]) * s, -__sinf(p[2]) * s); }
                    else { u0 = make_float2(__cosf(p[1]) * s, __sinf(p[1]) * s);
                           u1 = make_float2(__cosf(p[1] + p[2]) * c, __sinf(p[1] + p[2]) * c); }
#pragma unroll
                    for (int jj = 0; jj < 4; jj++) rowv[jj] = make_float2(0.f, 0.f);
                    rowv[i2] = u0; rowv[2 | i2] = u1;
                } else {
                    c32 coef0, coef1; int c0, c1;
                    if (step == 1 || step == 5) {              // XX
                        float s, c; __sincosf(p[step == 1 ? 3 : 9] * 0.5f, &s, &c);
                        c0 = i; coef0 = make_float2(c, 0.f);
                        c1 = i ^ 3; coef1 = make_float2(0.f, -s);
                    } else if (step == 2 || step == 6) {       // YY
                        float s, c; __sincosf(p[step == 2 ? 4 : 10] * 0.5f, &s, &c);
                        float yy = (i == 0 || i == 3) ? 1.f : -1.f;
                        c0 = i; coef0 = make_float2(c, 0.f);
                        c1 = i ^ 3; coef1 = make_float2(0.f, s * yy);
                    } else if (step == 3 || step == 7) {       // ZZ (diag)
                        float s, c; __sincosf(p[step == 3 ? 5 : 11] * 0.5f, &s, &c);
                        float zz = (i == 0 || i == 3) ? 1.f : -1.f;
                        c0 = i; coef0 = make_float2(c, -s * zz);
                        c1 = i; coef1 = make_float2(0.f, 0.f);
                    } else {                                    // step 4: U3b (high qubit)
                        float s, c; __sincosf(p[6] * 0.5f, &s, &c);
                        if (i1 == 0) { coef0 = make_float2(c, 0.f);
                                       coef1 = make_float2(-__cosf(p[8]) * s, -__sinf(p[8]) * s); }
                        else { coef0 = make_float2(__cosf(p[7]) * s, __sinf(p[7]) * s);
                               coef1 = make_float2(__cosf(p[7] + p[8]) * c, __sinf(p[7] + p[8]) * c); }
                        c0 = i2; c1 = 2 | i2;
                    }
#pragma unroll
                    for (int jj = 0; jj < 4; jj++)
                        rowv[jj] = cfma(coef0, src[c0 * 4 + jj], cmul(coef1, src[c1 * 4 + jj]));
                }
#pragma unroll
                for (int jj = 0; jj < 4; jj++) dst[i * 4 + jj] = rowv[jj];
            }
        }
        __syncthreads();
    }

    // ================= Phase 4: state-vector simulation (2 amps/thread) =================
    c32 v[2];
    v[0] = make_float2(0.f, 0.f);
    v[1] = make_float2(0.f, 0.f);
    if (t == 0) v[0] = make_float2(1.f, 0.f);

    // encoding: order (0,1)(2,3)(4,5)(6,7)(8,9)(1,2)(3,4)(5,6)(7,8);
    // (1,2),(3,4) hoisted before (6,7),(8,9) [disjoint wires commute]
    applyLocLane<0>(v, loadLocLane<0>(UeS + 0, ln));   // (0,1)
    applyL2<1, 2>(v, loadL2<1, 2>(UeS + 16, ln));      // (2,3)
    applyL2<3, 4>(v, loadL2<3, 4>(UeS + 32, ln));      // (4,5)
    applyL2<0, 1>(v, loadL2<0, 1>(UeS + 80, ln));      // (1,2)
    applyL2<2, 3>(v, loadL2<2, 3>(UeS + 96, ln));      // (3,4)
    dumpV2(v, psiA, t); __syncthreads();
    ldsApply2<6, 7>(loadF8(UeS + 48, rr), psiA, psiB, gg, rr); __syncthreads();   // (6,7)
    ldsApply2<8, 9>(loadF8(UeS + 64, rr), psiB, psiA, gg, rr); __syncthreads();   // (8,9)
    loadV2(v, psiA, t);
    applyL2<4, 5>(v, loadL2<4, 5>(UeS + 112, ln));     // (5,6)
    dumpV2(v, psiA, t); __syncthreads();
    ldsApply2<7, 8>(loadF8(UeS + 128, rr), psiA, psiB, gg, rr); __syncthreads();  // (7,8)
    loadV2(v, psiB, t);

    // pyramid (fully unrolled)
    {
        int g = 0;
#pragma unroll
        for (int layer = 0; layer < 9; layer++) {
            const int amax = 8 - layer;
            applyLocLane<0>(v, loadLocLane<0>(GpS + (g++) * 16, ln));            // (0,1)
            if (amax >= 1) applyL2<0, 1>(v, loadL2<0, 1>(GpS + (g++) * 16, ln)); // (1,2)
            if (amax >= 2) applyL2<1, 2>(v, loadL2<1, 2>(GpS + (g++) * 16, ln)); // (2,3)
            if (amax >= 3) applyL2<2, 3>(v, loadL2<2, 3>(GpS + (g++) * 16, ln)); // (3,4)
            if (amax >= 4) applyL2<3, 4>(v, loadL2<3, 4>(GpS + (g++) * 16, ln)); // (4,5)
            if (amax >= 5) applyL2<4, 5>(v, loadL2<4, 5>(GpS + (g++) * 16, ln)); // (5,6)
            if (amax >= 6) {
                dumpV2(v, psiA, t); __syncthreads();
                ldsApply2<6, 7>(loadF8(GpS + (g++) * 16, rr), psiA, psiB, gg, rr);  // (6,7)
                __syncthreads();
                if (amax >= 7) {
                    ldsApply2<7, 8>(loadF8(GpS + (g++) * 16, rr), psiB, psiA, gg, rr);  // (7,8)
                    __syncthreads();
                    if (amax >= 8) {
                        ldsApply2<8, 9>(loadF8(GpS + (g++) * 16, rr), psiA, psiB, gg, rr);  // (8,9)
                        __syncthreads();
                        loadV2(v, psiB, t);
                    } else {
                        loadV2(v, psiA, t);
                    }
                } else {
                    loadV2(v, psiB, t);
                }
            }
        }
    }

    // ================= Phase 5: observables (half-group per thread, DPP reduce) =================
    dumpV2(v, psiA, t);
    __syncthreads();
#pragma unroll
    for (int w0 = 0; w0 < NOBS; w0 += 5) {
        float pr[5];
#pragma unroll
        for (int u = 0; u < 5; u++) {
            const int w = w0 + u;
            const int pa = OAc[w], pb = OBc[w];  // pa < pb (identity wire map)
            const int oa = 1 << pa, ob = 1 << pb;
            int i0 = insert2(gg, pa, pb);
            const float* Hf = HbS + w * 16;
            c32 g0 = psiA[i0], g1 = psiA[i0 + ob], g2 = psiA[i0 + oa], g3 = psiA[i0 + oa + ob];
            float r;
            if (rr == 0) {
                // diag 0,1,2 + pairs (1,0),(2,0)
                r = Hf[0] * fmaf(g0.x, g0.x, g0.y * g0.y)
                  + Hf[1] * fmaf(g1.x, g1.x, g1.y * g1.y)
                  + Hf[2] * fmaf(g2.x, g2.x, g2.y * g2.y);
                float cx0 = fmaf(g1.x, g0.x, g1.y * g0.y);
                float cy0 = fmaf(g1.x, g0.y, -g1.y * g0.x);
                r = fmaf(Hf[4], cx0, r); r = fmaf(-Hf[5], cy0, r);
                float cx1 = fmaf(g2.x, g0.x, g2.y * g0.y);
                float cy1 = fmaf(g2.x, g0.y, -g2.y * g0.x);
                r = fmaf(Hf[6], cx1, r); r = fmaf(-Hf[7], cy1, r);
            } else {
                // pairs (2,1),(3,0),(3,1),(3,2)
                float cx0 = fmaf(g2.x, g1.x, g2.y * g1.y);
                float cy0 = fmaf(g2.x, g1.y, -g2.y * g1.x);
                r = Hf[8] * cx0 - Hf[9] * cy0;
                float cx1 = fmaf(g3.x, g0.x, g3.y * g0.y);
                float cy1 = fmaf(g3.x, g0.y, -g3.y * g0.x);
                r = fmaf(Hf[10], cx1, r); r = fmaf(-Hf[11], cy1, r);
                float cx2 = fmaf(g3.x, g1.x, g3.y * g1.y);
                float cy2 = fmaf(g3.x, g1.y, -g3.y * g1.x);
                r = fmaf(Hf[12], cx2, r); r = fmaf(-Hf[13], cy2, r);
                float cx3 = fmaf(g3.x, g2.x, g3.y * g2.y);
                float cy3 = fmaf(g3.x, g2.y, -g3.y * g2.x);
                r = fmaf(Hf[14], cx3, r); r = fmaf(-Hf[15], cy3, r);
            }
            pr[u] = wave_reduce63(r);
        }
        if (ln == 63) {
#pragma unroll
            for (int u = 0; u < 5; u++) redS[(w0 + u) * 8 + wv] = pr[u];
        }
    }
    __syncthreads();
    if (t < NOBS) {
        float s = 0.f;
#pragma unroll
        for (int k = 0; k < 8; k++) s += redS[t * 8 + k];
        out[(size_t)b * NOBS + t] = s;
    }
}

extern "C" void kernel_launch(void* const* d_in, const int* in_sizes, int n_in,
                              void* d_out, int out_size, void* d_ws, size_t ws_size,
                              hipStream_t stream) {
    (void)in_sizes; (void)n_in; (void)out_size; (void)d_ws; (void)ws_size;
    const float* x  = (const float*)d_in[0];
    const float* W1 = (const float*)d_in[1];
    const float* b1 = (const float*)d_in[2];
    const float* W2 = (const float*)d_in[3];
    const float* b2 = (const float*)d_in[4];
    const float* qp = (const float*)d_in[5];
    const float* Am = (const float*)d_in[6];
    const float* Bm = (const float*)d_in[7];
    const float* Dm = (const float*)d_in[8];
    float* out = (float*)d_out;

    hipLaunchKernelGGL(mega_kernel, dim3(256), dim3(512), 0, stream,
                       x, W1, b1, W2, b2, qp, Am, Bm, Dm, out);
}